// Round 1
// baseline (148.742 us; speedup 1.0000x reference)
//
#include <hip/hip_runtime.h>
#include <cstdint>
#include <cstddef>

// out[64,197,768] = concat(cls, patchify(images[64,3,224,224]) @ W^T + b)
// Fully fused: fp32 gather + bf16 convert in-register -> LDS -> MFMA.
// Zero workspace use, single kernel.
#define MTOT 12544   // 64*196
#define KTOT 768
#define NTOT 768

#define BM 128
#define BN 128
#define BK 64
#define NBLK_M 98    // 12544/128
#define NBLK_N 6     // 768/128
#define CLS_BLOCKS 48

typedef float  f32x4  __attribute__((ext_vector_type(4)));
typedef __bf16 bf16x8 __attribute__((ext_vector_type(8)));

__device__ __forceinline__ void cvt16_write(const float4* r, __bf16* dst) {
  bf16x8 o0, o1;
  o0[0]=(__bf16)r[0].x; o0[1]=(__bf16)r[0].y; o0[2]=(__bf16)r[0].z; o0[3]=(__bf16)r[0].w;
  o0[4]=(__bf16)r[1].x; o0[5]=(__bf16)r[1].y; o0[6]=(__bf16)r[1].z; o0[7]=(__bf16)r[1].w;
  o1[0]=(__bf16)r[2].x; o1[1]=(__bf16)r[2].y; o1[2]=(__bf16)r[2].z; o1[3]=(__bf16)r[2].w;
  o1[4]=(__bf16)r[3].x; o1[5]=(__bf16)r[3].y; o1[6]=(__bf16)r[3].z; o1[7]=(__bf16)r[3].w;
  *(bf16x8*)(dst)     = o0;
  *(bf16x8*)(dst + 8) = o1;
}

__global__ __launch_bounds__(256) void fused_kernel(
    const float* __restrict__ images, const float* __restrict__ Wm,
    const float* __restrict__ bias, const float* __restrict__ cls,
    float* __restrict__ out) {
  // LDS: [ks 0..1][row 0..127][k 0..31] bf16, 64B row stride (2-way = free)
  __shared__ __bf16 As[2 * 128 * 32];   // 16 KB
  __shared__ __bf16 Bs[2 * 128 * 32];   // 16 KB

  const int tid = threadIdx.x;
  const int bx  = blockIdx.x;

  // cls rows: 64*768 floats = 48 blocks * 256 thr * float4 (independent of GEMM output rows)
  if (bx < CLS_BLOCKS) {
    const int t  = bx * 256 + tid;
    const int bb = t / 192, r = t - bb * 192;   // 192 float4 per row
    *(float4*)(out + (size_t)bb * 197 * 768 + r * 4) = *(const float4*)(cls + r * 4);
  }

  // mblk-inner: consecutive blocks own disjoint A tiles -> each image byte fetched once per XCD
  const int mblk = bx % NBLK_M;
  const int nblk = bx / NBLK_M;
  const int m0 = mblk * BM, n0 = nblk * BN;
  const int wave = tid >> 6, lane = tid & 63;
  const int wm = (wave & 1) * 64;        // wave sub-tile 64(M) x 64(N)
  const int wn = (wave >> 1) * 64;
  const int lrow = lane & 15, lq = lane >> 4;

  // ---- A staging: 2 passes x 16 elems/thread. unit = s*256+tid; row=unit&127, jc=unit>>7
  //      k_in_tile = jc*16 + 0..15 -> one contiguous 64B image row-segment (16 px).
  //      ph = (kt&3)*4 + jc, c = kt>>2 -> wave-uniform per-kt advance.
  const float* pA[2];
  __bf16* lA[2];
#pragma unroll
  for (int s = 0; s < 2; ++s) {
    const int unit = s * 256 + tid;
    const int row = unit & 127, jc = unit >> 7;
    const int m = m0 + row;
    const int bb = m / 196, p = m - bb * 196;
    const int pi = p / 14, pj = p - pi * 14;
    pA[s] = images + ((size_t)(bb * 3 * 224) + pi * 16 + jc) * 224 + pj * 16;
    lA[s] = As + (jc >> 1) * 4096 + row * 32 + (jc & 1) * 16;
  }
  // ---- B staging: W[768h][768k] fp32. jc = tid&3 (4 threads cover 256B contiguous of one h-row)
  const float* pB[2];
  __bf16* lB[2];
#pragma unroll
  for (int s = 0; s < 2; ++s) {
    const int hrow = (tid >> 2) + s * 64;
    const int jc = tid & 3;
    pB[s] = Wm + (size_t)(n0 + hrow) * 768 + jc * 16;
    lB[s] = Bs + (jc >> 1) * 4096 + hrow * 32 + (jc & 1) * 16;
  }

  f32x4 acc[4][4] = {};
  float4 ra[2][4], rb[2][4];

  // prologue: loads for kt=0
#pragma unroll
  for (int s = 0; s < 2; ++s)
#pragma unroll
    for (int q = 0; q < 4; ++q) {
      ra[s][q] = *(const float4*)(pA[s] + q * 4);
      rb[s][q] = *(const float4*)(pB[s] + q * 4);
    }

  for (int kt = 0; kt < KTOT / BK; ++kt) {   // 12 iterations
    // convert + LDS write (consumes ra/rb of this kt)
#pragma unroll
    for (int s = 0; s < 2; ++s) {
      cvt16_write(ra[s], lA[s]);
      cvt16_write(rb[s], lB[s]);
    }
    __syncthreads();   // lgkmcnt(0) -> tiles visible

    // T14 async-stage: issue next tile's global loads now; MFMA phase hides the latency
    const int dA = ((kt & 3) == 3) ? 47488 : 896;  // +4 image rows, or channel-cross
    pA[0] += dA; pA[1] += dA; pB[0] += BK; pB[1] += BK;
    if (kt < KTOT / BK - 1) {
#pragma unroll
      for (int s = 0; s < 2; ++s)
#pragma unroll
        for (int q = 0; q < 4; ++q) {
          ra[s][q] = *(const float4*)(pA[s] + q * 4);
          rb[s][q] = *(const float4*)(pB[s] + q * 4);
        }
    }

#pragma unroll
    for (int ks = 0; ks < 2; ++ks) {
      bf16x8 af[4], bf[4];
#pragma unroll
      for (int i = 0; i < 4; ++i)
        af[i] = *(const bf16x8*)&As[ks * 4096 + (wm + i * 16 + lrow) * 32 + lq * 8];
#pragma unroll
      for (int j = 0; j < 4; ++j)
        bf[j] = *(const bf16x8*)&Bs[ks * 4096 + (wn + j * 16 + lrow) * 32 + lq * 8];
#pragma unroll
      for (int i = 0; i < 4; ++i)
#pragma unroll
        for (int j = 0; j < 4; ++j)
          acc[i][j] = __builtin_amdgcn_mfma_f32_16x16x32_bf16(af[i], bf[j], acc[i][j], 0, 0, 0);
    }
    __syncthreads();   // protect LDS from next kt's writes
  }

  // Epilogue: C/D layout col=lane&15, row=(lane>>4)*4+r (round-1-verified convention)
#pragma unroll
  for (int j = 0; j < 4; ++j) {
    const int h  = n0 + wn + j * 16 + lrow;
    const float bv = bias[h];
#pragma unroll
    for (int i = 0; i < 4; ++i) {
      const int mb = m0 + wm + i * 16 + lq * 4;
#pragma unroll
      for (int r = 0; r < 4; ++r) {
        const int m  = mb + r;
        const int bb = m / 196, p = m - bb * 196;
        out[(size_t)(bb * 197 + 1 + p) * 768 + h] = acc[i][j][r] + bv;
      }
    }
  }
}

extern "C" void kernel_launch(void* const* d_in, const int* in_sizes, int n_in,
                              void* d_out, int out_size, void* d_ws, size_t ws_size,
                              hipStream_t stream) {
  const float* images = (const float*)d_in[0];  // [64,3,224,224]
  const float* Wm     = (const float*)d_in[1];  // [768,768]
  const float* b      = (const float*)d_in[2];  // [768]
  const float* cls    = (const float*)d_in[3];  // [1,768]
  float* out = (float*)d_out;                   // [64,197,768]
  (void)in_sizes; (void)n_in; (void)out_size; (void)d_ws; (void)ws_size;

  fused_kernel<<<NBLK_M * NBLK_N, 256, 0, stream>>>(images, Wm, b, cls, out);
}